// Round 4
// baseline (131.473 us; speedup 1.0000x reference)
//
#include <hip/hip_runtime.h>

// T=8192 frames, D=256, P=64 phones, K=128 centers/phone
#define T_FRAMES 8192
#define D_DIM    256
#define P_PHONES 64
#define K_CENT   128
#define TILE_F   16
#define BUCKET_CAP 256       // max per-phone count ~128+11sigma, safe
#define SLOTS_PP   16        // 256/16 slots per phone
#define MARGIN   1.0f        // f16 coarse d2 error bound (worst ~0.4) -> 2.5x headroom

// ws byte layout
#define WS_NORMS  0                      // float[8192]            32 KB
#define WS_FIDX   32768                  // int[64*256]            64 KB
#define WS_SCNT   98304                  // int[1024]               4 KB
#define WS_HH     102400                 // _Float16[8192*256]      4 MB  (stores -2*h)
#define WS_CH     (102400 + 4194304)     // _Float16[64*128*256]    4 MB

typedef _Float16 half8 __attribute__((ext_vector_type(8)));
typedef float    f32x4 __attribute__((ext_vector_type(4)));

// ---------------- K1: prep ----------------
// b 0..511:   convert h -> -2h f16 (hH), centers -> f16 (cH), fused center norms
// b 512..575: bucket block for phone j = b-512; pads fidx to 256 with a valid
//             frame of the same phone; writes flat slotcnt[] (no desc indirection)
__global__ __launch_bounds__(1024) void qr_prep_kernel(const float* __restrict__ h,
                                                       const float* __restrict__ centers,
                                                       const int* __restrict__ phones,
                                                       float* __restrict__ norms,
                                                       int* __restrict__ fidx,
                                                       int* __restrict__ slotcnt,
                                                       _Float16* __restrict__ hH,
                                                       _Float16* __restrict__ cH) {
    const int b    = blockIdx.x;
    const int tid  = threadIdx.x;
    const int w    = tid >> 6;
    const int lane = tid & 63;

    if (b < 512) {
        const size_t e = ((size_t)b * 1024 + tid) * 4;
        union { _Float16 hf[4]; uint2 u; } pk;
        float4 v = *(const float4*)(h + e);
        pk.hf[0] = (_Float16)(-2.f * v.x); pk.hf[1] = (_Float16)(-2.f * v.y);
        pk.hf[2] = (_Float16)(-2.f * v.z); pk.hf[3] = (_Float16)(-2.f * v.w);
        *(uint2*)(hH + e) = pk.u;
        v = *(const float4*)(centers + e);
        pk.hf[0] = (_Float16)v.x; pk.hf[1] = (_Float16)v.y;
        pk.hf[2] = (_Float16)v.z; pk.hf[3] = (_Float16)v.w;
        *(uint2*)(cH + e) = pk.u;
        float s = v.x * v.x + v.y * v.y + v.z * v.z + v.w * v.w;
#pragma unroll
        for (int off = 32; off; off >>= 1) s += __shfl_xor(s, off, 64);
        if (lane == 0) norms[b * 16 + w] = s;   // wave w == center row b*16+w
        return;
    }

    // bucket block: 16 waves, wave w scans frames [w*512, w*512+512)
    __shared__ int nsh;
    __shared__ int sF0;
    const int j = b - 512;
    if (tid == 0) { nsh = 0; sF0 = 0; }
    __syncthreads();
#pragma unroll
    for (int ch = 0; ch < 8; ++ch) {
        const int f = w * 512 + ch * 64 + lane;
        const bool mt = (phones[f] == j);
        const unsigned long long mask = __ballot(mt);
        const int cnt = __popcll(mask);
        if (cnt) {
            int base = 0;
            if (lane == 0) base = atomicAdd(&nsh, cnt);
            base = __shfl(base, 0, 64);
            if (mt) {
                const int pos = base + __popcll(mask & ((1ull << lane) - 1ull));
                if (pos < BUCKET_CAP) fidx[j * BUCKET_CAP + pos] = f;
                if (pos == 0) sF0 = f;
            }
        }
    }
    __syncthreads();
    const int c = nsh > BUCKET_CAP ? BUCKET_CAP : nsh;
    const int f0 = sF0;
    for (int pos = c + tid; pos < BUCKET_CAP; pos += 1024) fidx[j * BUCKET_CAP + pos] = f0;
    if (tid < SLOTS_PP) {
        const int rem = c - tid * TILE_F;
        slotcnt[j * SLOTS_PP + tid] = rem < 0 ? 0 : (rem > TILE_F ? TILE_F : rem);
    }
}

// ---------------- K2: main ----------------
// block = one 16-frame tile x 128 centers; wave w owns centers [w*32, w*32+32).
// All operand loads issued up-front and pinned above the MFMAs (sched_barrier)
// so ~34 misses overlap instead of serializing. -2 pre-folded into hH; ||c||^2
// is the MFMA C-init so acc IS coarse d2. XCD-bijective slot swizzle keeps all
// 16 slots of a phone on one XCD for L2 pool reuse.
__global__ __launch_bounds__(256, 4) void qr_main_kernel(const float* __restrict__ h,
                                                         const float* __restrict__ centers,
                                                         const float* __restrict__ norms,
                                                         const int* __restrict__ fidx,
                                                         const int* __restrict__ slotcnt,
                                                         const _Float16* __restrict__ hH,
                                                         const _Float16* __restrict__ cH,
                                                         float* __restrict__ out) {
    __shared__ float sMin[4][TILE_F];
    __shared__ int   sCnt[4][TILE_F];
    __shared__ int   sCand[4][TILE_F];
    __shared__ int   sWin[TILE_F];
    __shared__ int   sRl[TILE_F];
    __shared__ int   sRn;

    const int bid  = blockIdx.x;
    const int slot = ((bid & 7) << 7) | (bid >> 3);   // bijective: phone-per-XCD grouping
    const int p    = slot >> 4;

    const int tid  = threadIdx.x;
    const int wave = tid >> 6;
    const int lane = tid & 63;
    const int m    = lane & 15;
    const int quad = lane >> 4;

    if (tid == 0) sRn = 0;

    // level-1 loads in parallel: slot count + frame index (fstart == slot*16)
    const int fcnt = slotcnt[slot];
    const int fiA  = fidx[slot * TILE_F + m];          // padded -> always valid
    if (fcnt == 0) return;                             // block-uniform exit

    // level-2: issue ALL MFMA operand loads back-to-back
    half8 aF[8];
    const _Float16* ap = hH + ((size_t)fiA << 8) + quad * 8;
#pragma unroll
    for (int s = 0; s < 8; ++s) aF[s] = *(const half8*)(ap + s * 32);

    half8 bF[2][8];
    const _Float16* bp = cH + (((size_t)(p << 7) + (wave << 5) + m) << 8) + quad * 8;
#pragma unroll
    for (int ch = 0; ch < 2; ++ch)
#pragma unroll
        for (int s = 0; s < 8; ++s)
            bF[ch][s] = *(const half8*)(bp + (ch << 12) + s * 32);

    const float nrm0 = norms[(p << 7) + (wave << 5) + m];
    const float nrm1 = norms[(p << 7) + (wave << 5) + 16 + m];
    __builtin_amdgcn_sched_barrier(0);   // pin loads above: no sinking into MFMA loop

    f32x4 acc[2];
    acc[0] = f32x4{nrm0, nrm0, nrm0, nrm0};
    acc[1] = f32x4{nrm1, nrm1, nrm1, nrm1};
#pragma unroll
    for (int s = 0; s < 8; ++s) {
        acc[0] = __builtin_amdgcn_mfma_f32_16x16x32_f16(aF[s], bF[0][s], acc[0], 0, 0, 0);
        acc[1] = __builtin_amdgcn_mfma_f32_16x16x32_f16(aF[s], bF[1][s], acc[1], 0, 0, 0);
    }

    // per-frame partial min over this wave's 32 centers (16-lane shfl groups)
#pragma unroll
    for (int r = 0; r < 4; ++r) {
        float mn = fminf(acc[0][r], acc[1][r]);
#pragma unroll
        for (int off = 1; off <= 8; off <<= 1) mn = fminf(mn, __shfl_xor(mn, off, 64));
        if (m == 0) sMin[wave][quad * 4 + r] = mn;
    }
    __syncthreads();

    // global tau per frame; count candidates in this wave's slice
#pragma unroll
    for (int r = 0; r < 4; ++r) {
        const int f = quad * 4 + r;
        const float gm = fminf(fminf(sMin[0][f], sMin[1][f]), fminf(sMin[2][f], sMin[3][f]));
        const float tau = gm + MARGIN;
        int cnt = 0, cand = 0x7FFFFFFF;
#pragma unroll
        for (int ch = 0; ch < 2; ++ch) {
            if (acc[ch][r] < tau) { ++cnt; cand = min(cand, (wave << 5) + ch * 16 + m); }
        }
#pragma unroll
        for (int off = 1; off <= 8; off <<= 1) {
            cnt += __shfl_xor(cnt, off, 64);
            cand = min(cand, __shfl_xor(cand, off, 64));
        }
        if (m == 0) { sCnt[wave][f] = cnt; sCand[wave][f] = cand; }
    }
    __syncthreads();

    // combine: unique candidate -> winner; else enqueue exact rescue
    if (tid < TILE_F) {
        const int tc = sCnt[0][tid] + sCnt[1][tid] + sCnt[2][tid] + sCnt[3][tid];
        const int cd = min(min(sCand[0][tid], sCand[1][tid]), min(sCand[2][tid], sCand[3][tid]));
        if (tc == 1) sWin[tid] = cd;
        else if (tid < fcnt) sRl[atomicAdd(&sRn, 1)] = tid;
    }
    __syncthreads();

    // exact fp32 rescue (rare): one wave per listed frame, rolled loop
    const int rn = sRn;
    for (int ridx = wave; ridx < rn; ridx += 4) {
        const int f2 = sRl[ridx];
        const int fi = fidx[slot * TILE_F + f2];
        const float4* hp  = (const float4*)(h + (size_t)fi * D_DIM);
        const float4* cp0 = (const float4*)(centers + ((size_t)(p << 7) + lane) * D_DIM);
        float s0 = 0.f, s1 = 0.f;
#pragma unroll 4
        for (int jx = 0; jx < 64; ++jx) {
            const float4 a  = hp[jx];
            const float4 b0 = cp0[jx];
            const float4 b1 = cp0[jx + 4096];          // center row lane+64
            s0 += a.x * b0.x + a.y * b0.y + a.z * b0.z + a.w * b0.w;
            s1 += a.x * b1.x + a.y * b1.y + a.z * b1.z + a.w * b1.w;
        }
        float best = norms[(p << 7) + lane] - 2.f * s0;
        int   bc   = lane;
        const float d1 = norms[(p << 7) + lane + 64] - 2.f * s1;
        if (d1 < best) { best = d1; bc = lane + 64; }  // lane+64 > lane: strict < keeps tie rule
#pragma unroll
        for (int off = 1; off < 64; off <<= 1) {       // lexicographic (d2, c) min -> jnp ties
            const float ob = __shfl_xor(best, off, 64);
            const int   oc = __shfl_xor(bc, off, 64);
            if (ob < best || (ob == best && oc < bc)) { best = ob; bc = oc; }
        }
        if (lane == 0) sWin[f2] = bc;
    }
    __syncthreads();

    // copy winning rows: 16 threads/frame, 4 float4 each
    const int f = tid >> 4, part = tid & 15;
    if (f < fcnt) {
        const int fo = fidx[slot * TILE_F + f];
        const float4* src = (const float4*)(centers + ((size_t)(p << 7) + sWin[f]) * D_DIM);
        float4*       dst = (float4*)(out + (size_t)fo * D_DIM);
#pragma unroll
        for (int jx = 0; jx < 4; ++jx) dst[part + 16 * jx] = src[part + 16 * jx];
    }
}

extern "C" void kernel_launch(void* const* d_in, const int* in_sizes, int n_in,
                              void* d_out, int out_size, void* d_ws, size_t ws_size,
                              hipStream_t stream) {
    const float* h       = (const float*)d_in[0];
    const float* centers = (const float*)d_in[1];
    const int*   phones  = (const int*)d_in[2];
    float*       out     = (float*)d_out;

    char* ws = (char*)d_ws;
    float*    norms   = (float*)(ws + WS_NORMS);
    int*      fidx    = (int*)(ws + WS_FIDX);
    int*      slotcnt = (int*)(ws + WS_SCNT);
    _Float16* hH      = (_Float16*)(ws + WS_HH);
    _Float16* cH      = (_Float16*)(ws + WS_CH);

    qr_prep_kernel<<<576, 1024, 0, stream>>>(h, centers, phones, norms, fidx, slotcnt, hH, cH);
    qr_main_kernel<<<P_PHONES * SLOTS_PP, 256, 0, stream>>>(h, centers, norms, fidx, slotcnt, hH, cH, out);
}

// Round 5
// 90.827 us; speedup vs baseline: 1.4475x; 1.4475x over previous
//
#include <hip/hip_runtime.h>

// T=8192 frames, D=256, P=64 phones, K=128 centers/phone
#define T_FRAMES 8192
#define D_DIM    256
#define P_PHONES 64
#define K_CENT   128
#define TILE_F   16
#define BUCKET_CAP 256       // max per-phone count ~128+11sigma, safe
#define SLOTS_PP   16        // 256/16 slots per phone
#define MARGIN   1.0f        // f16 coarse d2 error bound (worst ~0.4) -> 2.5x headroom
#define NC_MAX   4           // candidate-list cap; tc>4 falls back to full scan

// ws byte layout
#define WS_NORMS  0                      // float[8192]            32 KB
#define WS_FIDX   32768                  // int[64*256]            64 KB
#define WS_SCNT   98304                  // int[1024]               4 KB
#define WS_HH     102400                 // _Float16[8192*256]      4 MB  (stores -2*h)
#define WS_CH     (102400 + 4194304)     // _Float16[64*128*256]    4 MB

typedef _Float16 half8 __attribute__((ext_vector_type(8)));
typedef float    f32x4 __attribute__((ext_vector_type(4)));

// ---------------- K1: prep ----------------
// b 0..511:   convert h -> -2h f16 (hH), centers -> f16 (cH), fused center norms
// b 512..575: bucket block for phone j = b-512; pads fidx to 256 with a valid
//             frame of the same phone; writes flat slotcnt[] (no desc indirection)
__global__ __launch_bounds__(1024) void qr_prep_kernel(const float* __restrict__ h,
                                                       const float* __restrict__ centers,
                                                       const int* __restrict__ phones,
                                                       float* __restrict__ norms,
                                                       int* __restrict__ fidx,
                                                       int* __restrict__ slotcnt,
                                                       _Float16* __restrict__ hH,
                                                       _Float16* __restrict__ cH) {
    const int b    = blockIdx.x;
    const int tid  = threadIdx.x;
    const int w    = tid >> 6;
    const int lane = tid & 63;

    if (b < 512) {
        const size_t e = ((size_t)b * 1024 + tid) * 4;
        union { _Float16 hf[4]; uint2 u; } pk;
        float4 v = *(const float4*)(h + e);
        pk.hf[0] = (_Float16)(-2.f * v.x); pk.hf[1] = (_Float16)(-2.f * v.y);
        pk.hf[2] = (_Float16)(-2.f * v.z); pk.hf[3] = (_Float16)(-2.f * v.w);
        *(uint2*)(hH + e) = pk.u;
        v = *(const float4*)(centers + e);
        pk.hf[0] = (_Float16)v.x; pk.hf[1] = (_Float16)v.y;
        pk.hf[2] = (_Float16)v.z; pk.hf[3] = (_Float16)v.w;
        *(uint2*)(cH + e) = pk.u;
        float s = v.x * v.x + v.y * v.y + v.z * v.z + v.w * v.w;
#pragma unroll
        for (int off = 32; off; off >>= 1) s += __shfl_xor(s, off, 64);
        if (lane == 0) norms[b * 16 + w] = s;   // wave w == center row b*16+w
        return;
    }

    // bucket block: 16 waves, wave w scans frames [w*512, w*512+512)
    __shared__ int nsh;
    __shared__ int sF0;
    const int j = b - 512;
    if (tid == 0) { nsh = 0; sF0 = 0; }
    __syncthreads();
#pragma unroll
    for (int ch = 0; ch < 8; ++ch) {
        const int f = w * 512 + ch * 64 + lane;
        const bool mt = (phones[f] == j);
        const unsigned long long mask = __ballot(mt);
        const int cnt = __popcll(mask);
        if (cnt) {
            int base = 0;
            if (lane == 0) base = atomicAdd(&nsh, cnt);
            base = __shfl(base, 0, 64);
            if (mt) {
                const int pos = base + __popcll(mask & ((1ull << lane) - 1ull));
                if (pos < BUCKET_CAP) fidx[j * BUCKET_CAP + pos] = f;
                if (pos == 0) sF0 = f;
            }
        }
    }
    __syncthreads();
    const int c = nsh > BUCKET_CAP ? BUCKET_CAP : nsh;
    const int f0 = sF0;
    for (int pos = c + tid; pos < BUCKET_CAP; pos += 1024) fidx[j * BUCKET_CAP + pos] = f0;
    if (tid < SLOTS_PP) {
        const int rem = c - tid * TILE_F;
        slotcnt[j * SLOTS_PP + tid] = rem < 0 ? 0 : (rem > TILE_F ? TILE_F : rem);
    }
}

// ---------------- K2: main ----------------
// block = one 16-frame tile x 128 centers; wave w owns centers [w*32, w*32+32).
// Coarse f16 MFMA d2 (operands pinned above MFMAs), candidate indices collected
// into LDS (cap 4); exact fp32 rescue touches ONLY the candidates: h-row + <=4
// center rows fetched in a single latency exposure, 64-lane tree dots, lex
// (d2, c) pick. Full-scan fallback only if tc > 4 (~never).
__global__ __launch_bounds__(256, 4) void qr_main_kernel(const float* __restrict__ h,
                                                         const float* __restrict__ centers,
                                                         const float* __restrict__ norms,
                                                         const int* __restrict__ fidx,
                                                         const int* __restrict__ slotcnt,
                                                         const _Float16* __restrict__ hH,
                                                         const _Float16* __restrict__ cH,
                                                         float* __restrict__ out) {
    __shared__ float sMin[4][TILE_F];
    __shared__ int   sNc[TILE_F];
    __shared__ int   sCl[TILE_F][NC_MAX];
    __shared__ int   sWin[TILE_F];
    __shared__ int   sRl[TILE_F];
    __shared__ int   sRn;

    const int bid  = blockIdx.x;
    const int slot = ((bid & 7) << 7) | (bid >> 3);   // bijective: phone-per-XCD grouping
    const int p    = slot >> 4;

    const int tid  = threadIdx.x;
    const int wave = tid >> 6;
    const int lane = tid & 63;
    const int m    = lane & 15;
    const int quad = lane >> 4;

    if (tid == 0) sRn = 0;
    if (tid < TILE_F) sNc[tid] = 0;

    // level-1 loads in parallel: slot count + frame index (fstart == slot*16)
    const int fcnt = slotcnt[slot];
    const int fiA  = fidx[slot * TILE_F + m];          // padded -> always valid
    if (fcnt == 0) return;                             // block-uniform exit

    // level-2: issue ALL MFMA operand loads back-to-back
    half8 aF[8];
    const _Float16* ap = hH + ((size_t)fiA << 8) + quad * 8;
#pragma unroll
    for (int s = 0; s < 8; ++s) aF[s] = *(const half8*)(ap + s * 32);

    half8 bF[2][8];
    const _Float16* bp = cH + (((size_t)(p << 7) + (wave << 5) + m) << 8) + quad * 8;
#pragma unroll
    for (int ch = 0; ch < 2; ++ch)
#pragma unroll
        for (int s = 0; s < 8; ++s)
            bF[ch][s] = *(const half8*)(bp + (ch << 12) + s * 32);

    const float nrm0 = norms[(p << 7) + (wave << 5) + m];
    const float nrm1 = norms[(p << 7) + (wave << 5) + 16 + m];
    __builtin_amdgcn_sched_barrier(0);   // pin loads above: no sinking into MFMA loop

    f32x4 acc[2];
    acc[0] = f32x4{nrm0, nrm0, nrm0, nrm0};
    acc[1] = f32x4{nrm1, nrm1, nrm1, nrm1};
#pragma unroll
    for (int s = 0; s < 8; ++s) {
        acc[0] = __builtin_amdgcn_mfma_f32_16x16x32_f16(aF[s], bF[0][s], acc[0], 0, 0, 0);
        acc[1] = __builtin_amdgcn_mfma_f32_16x16x32_f16(aF[s], bF[1][s], acc[1], 0, 0, 0);
    }

    // per-frame partial min over this wave's 32 centers (16-lane shfl groups)
#pragma unroll
    for (int r = 0; r < 4; ++r) {
        float mn = fminf(acc[0][r], acc[1][r]);
#pragma unroll
        for (int off = 1; off <= 8; off <<= 1) mn = fminf(mn, __shfl_xor(mn, off, 64));
        if (m == 0) sMin[wave][quad * 4 + r] = mn;
    }
    __syncthreads();

    // global tau per frame; append candidate indices to LDS list (cap NC_MAX)
#pragma unroll
    for (int r = 0; r < 4; ++r) {
        const int f = quad * 4 + r;
        const float gm = fminf(fminf(sMin[0][f], sMin[1][f]), fminf(sMin[2][f], sMin[3][f]));
        const float tau = gm + MARGIN;
#pragma unroll
        for (int ch = 0; ch < 2; ++ch) {
            if (acc[ch][r] < tau) {
                const int pos = atomicAdd(&sNc[f], 1);
                if (pos < NC_MAX) sCl[f][pos] = (wave << 5) + ch * 16 + m;
            }
        }
    }
    __syncthreads();

    // classify: unique candidate -> winner; else enqueue exact rescue
    if (tid < TILE_F) {
        if (sNc[tid] == 1) sWin[tid] = sCl[tid][0];
        else if (tid < fcnt) sRl[atomicAdd(&sRn, 1)] = tid;
    }
    __syncthreads();

    // exact fp32 rescue: one wave per listed frame
    const int rn = sRn;
    for (int ridx = wave; ridx < rn; ridx += 4) {
        const int f2 = sRl[ridx];
        const int fi = fidx[slot * TILE_F + f2];
        const int tc = sNc[f2];
        if (tc <= NC_MAX) {
            // candidate path: h-row + <=4 center rows in ONE latency exposure
            int cl[NC_MAX];
            cl[0] = sCl[f2][0];
#pragma unroll
            for (int k = 1; k < NC_MAX; ++k) cl[k] = (k < tc) ? sCl[f2][k] : cl[0];
            const float4 hv = ((const float4*)(h + (size_t)fi * D_DIM))[lane];
            float4 cv[NC_MAX];
#pragma unroll
            for (int k = 0; k < NC_MAX; ++k)
                cv[k] = ((const float4*)(centers + ((size_t)(p << 7) + cl[k]) * D_DIM))[lane];
            float s[NC_MAX];
#pragma unroll
            for (int k = 0; k < NC_MAX; ++k)
                s[k] = hv.x * cv[k].x + hv.y * cv[k].y + hv.z * cv[k].z + hv.w * cv[k].w;
#pragma unroll
            for (int off = 1; off < 64; off <<= 1)
#pragma unroll
                for (int k = 0; k < NC_MAX; ++k) s[k] += __shfl_xor(s[k], off, 64);
            float best = norms[(p << 7) + cl[0]] - 2.f * s[0];
            int   bc   = cl[0];
#pragma unroll
            for (int k = 1; k < NC_MAX; ++k) {          // lex (d2, c) min -> jnp tie rule
                const float dk = norms[(p << 7) + cl[k]] - 2.f * s[k];
                if (dk < best || (dk == best && cl[k] < bc)) { best = dk; bc = cl[k]; }
            }
            if (lane == 0) sWin[f2] = bc;
        } else {
            // fallback: full 128-center scan (verified r4 path; ~never taken)
            const float4* hp  = (const float4*)(h + (size_t)fi * D_DIM);
            const float4* cp0 = (const float4*)(centers + ((size_t)(p << 7) + lane) * D_DIM);
            float s0 = 0.f, s1 = 0.f;
#pragma unroll 4
            for (int jx = 0; jx < 64; ++jx) {
                const float4 a  = hp[jx];
                const float4 b0 = cp0[jx];
                const float4 b1 = cp0[jx + 4096];      // center row lane+64
                s0 += a.x * b0.x + a.y * b0.y + a.z * b0.z + a.w * b0.w;
                s1 += a.x * b1.x + a.y * b1.y + a.z * b1.z + a.w * b1.w;
            }
            float best = norms[(p << 7) + lane] - 2.f * s0;
            int   bc   = lane;
            const float d1 = norms[(p << 7) + lane + 64] - 2.f * s1;
            if (d1 < best) { best = d1; bc = lane + 64; }
#pragma unroll
            for (int off = 1; off < 64; off <<= 1) {
                const float ob = __shfl_xor(best, off, 64);
                const int   oc = __shfl_xor(bc, off, 64);
                if (ob < best || (ob == best && oc < bc)) { best = ob; bc = oc; }
            }
            if (lane == 0) sWin[f2] = bc;
        }
    }
    __syncthreads();

    // copy winning rows: 16 threads/frame, 4 float4 each
    const int f = tid >> 4, part = tid & 15;
    if (f < fcnt) {
        const int fo = fidx[slot * TILE_F + f];
        const float4* src = (const float4*)(centers + ((size_t)(p << 7) + sWin[f]) * D_DIM);
        float4*       dst = (float4*)(out + (size_t)fo * D_DIM);
#pragma unroll
        for (int jx = 0; jx < 4; ++jx) dst[part + 16 * jx] = src[part + 16 * jx];
    }
}

extern "C" void kernel_launch(void* const* d_in, const int* in_sizes, int n_in,
                              void* d_out, int out_size, void* d_ws, size_t ws_size,
                              hipStream_t stream) {
    const float* h       = (const float*)d_in[0];
    const float* centers = (const float*)d_in[1];
    const int*   phones  = (const int*)d_in[2];
    float*       out     = (float*)d_out;

    char* ws = (char*)d_ws;
    float*    norms   = (float*)(ws + WS_NORMS);
    int*      fidx    = (int*)(ws + WS_FIDX);
    int*      slotcnt = (int*)(ws + WS_SCNT);
    _Float16* hH      = (_Float16*)(ws + WS_HH);
    _Float16* cH      = (_Float16*)(ws + WS_CH);

    qr_prep_kernel<<<576, 1024, 0, stream>>>(h, centers, phones, norms, fidx, slotcnt, hH, cH);
    qr_main_kernel<<<P_PHONES * SLOTS_PP, 256, 0, stream>>>(h, centers, norms, fidx, slotcnt, hH, cH, out);
}